// Round 14
// baseline (232.338 us; speedup 1.0000x reference)
//
#include <hip/hip_runtime.h>

#define NPTS   20000
#define NCHUNK 313   // ceil(NPTS/64)

typedef __bf16 bf16x8 __attribute__((ext_vector_type(8)));
typedef float  f32x4  __attribute__((ext_vector_type(4)));

__device__ __forceinline__ unsigned short f2b(float f) {
    __bf16 h = (__bf16)f;                       // RNE fptrunc (hw cvt on gfx950)
    union { __bf16 h; unsigned short s; } u; u.h = h; return u.s;
}
__device__ __forceinline__ unsigned int pk2(float a, float b) {
    return (unsigned int)f2b(a) | ((unsigned int)f2b(b) << 16);
}

// ---------------- workspace layout ----------------
#define WS_BINNED    0          // 40000 float4 = 640000 B
#define WS_PARTHIST  640000     // 40*512 u32  =  81920 B
#define WS_COUNTS    721920     // 1024 u32
#define WS_OFFSETS   726016     // 1024 u32
#define WS_FLAGS     730112     // (unused since R18; kept for layout stability)
#define WS_W2P       730368     // 128*64  bf16 = 16384 B (BN2-scaled, packed)
#define WS_W3P       746752     // 256*128 bf16 = 65536 B (BN3-scaled, packed)
#define WS_W1E       812288     // 64*3 f32
#define WS_B1E       813056     // 64 f32
#define WS_B2E       813312     // 128 f32
#define WS_B3E       813824     // 256 f32
#define WS_IDX       814848     // 2048*4*64 u16 = 1048576 B (selected indices)

// =============== prep = 2 kernels (scan folded into scatter) ===============
__global__ __launch_bounds__(512)
void hist_prepack_kernel(const float* __restrict__ pointcloud,
                const float* __restrict__ w1,
                const float* __restrict__ g1,  const float* __restrict__ be1,
                const float* __restrict__ mn1, const float* __restrict__ vr1,
                const float* __restrict__ w2,
                const float* __restrict__ g2,  const float* __restrict__ be2,
                const float* __restrict__ mn2, const float* __restrict__ vr2,
                const float* __restrict__ w3,
                const float* __restrict__ g3,  const float* __restrict__ be3,
                const float* __restrict__ mn3, const float* __restrict__ vr3,
                unsigned int* __restrict__ parthist,
                unsigned short* __restrict__ w2p,
                unsigned short* __restrict__ w3p,
                float* __restrict__ w1e_g, float* __restrict__ b1e_g,
                float* __restrict__ b2e_g, float* __restrict__ b3e_g)
{
    __shared__ unsigned int h[512];
    const int blk = blockIdx.x;          // 0..39
    const int b   = blk / 20;
    const int p   = blk % 20;
    const int tid = threadIdx.x;
    const int gid = blk * 512 + tid;     // 0..20479

    // ---- weight pre-pack (spread across all threads) ----
    for (int e = gid; e < 8192; e += 20480) {          // w2p[128][64]
        int row = e >> 6;
        float inv = g2[row] / sqrtf(vr2[row] + 1e-5f);
        w2p[e] = f2b(w2[e] * inv);
    }
    for (int e = gid; e < 32768; e += 20480) {         // w3p[256][128]
        int row = e >> 7;
        float inv = g3[row] / sqrtf(vr3[row] + 1e-5f);
        w3p[e] = f2b(w3[e] * inv);
    }
    if (gid < 64) {
        float inv = g1[gid] / sqrtf(vr1[gid] + 1e-5f);
        w1e_g[gid*3+0] = inv * w1[gid*3+0];
        w1e_g[gid*3+1] = inv * w1[gid*3+1];
        w1e_g[gid*3+2] = inv * w1[gid*3+2];
        b1e_g[gid]     = be1[gid] - mn1[gid] * inv;
    }
    if (gid < 128) {
        float inv = g2[gid] / sqrtf(vr2[gid] + 1e-5f);
        b2e_g[gid] = be2[gid] - mn2[gid] * inv;
    }
    if (gid < 256) {
        float inv = g3[gid] / sqrtf(vr3[gid] + 1e-5f);
        b3e_g[gid] = be3[gid] - mn3[gid] * inv;
    }

    // ---- histogram of own 1000-point slice ----
    h[tid] = 0;
    __syncthreads();

    const float* base = pointcloud + (b * NPTS + p * 1000) * 3;
    for (int i = tid; i < 1000; i += 512) {
        float x = base[i*3+0], y = base[i*3+1], z = base[i*3+2];
        int cx = min(7, (int)(x * 16.0f));
        int cy = min(7, (int)(y * 16.0f));
        int cz = min(7, (int)(z * 16.0f));
        atomicAdd(&h[(cz * 8 + cy) * 8 + cx], 1u);
    }
    __syncthreads();

    parthist[blk * 512 + tid] = h[tid];   // plain store; stream orders K1->K2
}

__global__ __launch_bounds__(512)
void scatter_kernel(const float* __restrict__ pointcloud,
                    const unsigned int* __restrict__ parthist,
                    unsigned int* __restrict__ counts,
                    unsigned int* __restrict__ offsets,
                    float4* __restrict__ binned)
{
    __shared__ unsigned int scanv[512];
    __shared__ unsigned int cur[512];
    const int blk = blockIdx.x;          // 0..39
    const int b   = blk / 20;
    const int p   = blk % 20;
    const int tid = threadIdx.x;

    unsigned int cnt = 0, partial = 0;
    #pragma unroll
    for (int pp = 0; pp < 20; ++pp) {
        unsigned int v = parthist[(b * 20 + pp) * 512 + tid];
        cnt += v;
        if (pp < p) partial += v;
    }
    scanv[tid] = cnt;
    __syncthreads();
    #pragma unroll
    for (int off = 1; off < 512; off <<= 1) {
        unsigned int v = 0;
        if (tid >= off) v = scanv[tid - off];
        __syncthreads();
        scanv[tid] += v;
        __syncthreads();
    }
    unsigned int excl = scanv[tid] - cnt;
    if (p == 0) {
        counts [b * 512 + tid] = cnt;
        offsets[b * 512 + tid] = b * NPTS + excl;
    }
    cur[tid] = b * NPTS + excl + partial;
    __syncthreads();

    const float* base = pointcloud + (b * NPTS + p * 1000) * 3;
    for (int i = tid; i < 1000; i += 512) {
        float x = base[i*3+0], y = base[i*3+1], z = base[i*3+2];
        int cx = min(7, (int)(x * 16.0f));
        int cy = min(7, (int)(y * 16.0f));
        int cz = min(7, (int)(z * 16.0f));
        int cid = (cz * 8 + cy) * 8 + cx;
        unsigned int slot = atomicAdd(&cur[cid], 1u);
        binned[slot] = make_float4(x, y, z, __int_as_float(p * 1000 + i));
    }
}

// =============== K_scan: scan + stage B (R29 shape, unchanged) =============
struct __align__(16) SMemS {
    unsigned int bm[4][640];    // 10240 B
    int cstart[64];
    int ccnt[64];
    int idxs[4][64];
};

__global__ __launch_bounds__(256, 6)
void scan_select_kernel(const float* __restrict__ seed_xyz,
                        const float* __restrict__ vp_rot,
                        const unsigned int* __restrict__ counts,
                        const unsigned int* __restrict__ offsets,
                        const float4* __restrict__ binned,
                        unsigned short* __restrict__ idx_out)
{
    __shared__ SMemS sm;
    const int tid = threadIdx.x;
    const int wv  = tid >> 6;
    const int ln  = tid & 63;

    const int blk = blockIdx.x;
    const int i8  = blk >> 3;
    const int s   = (blk & 7) * 128 + (i8 & 127);
    const int b   = i8 >> 7;
    const int bs  = b * 1024 + s;

    {
        unsigned int* bmp = &sm.bm[0][0];
        #pragma unroll
        for (int i = 0; i < 10; ++i) bmp[tid + i * 256] = 0;
    }

    const float sx = seed_xyz[bs*3+0];
    const float sy = seed_xyz[bs*3+1];
    const float sz = seed_xyz[bs*3+2];
    const float R00 = vp_rot[bs*9+0], R01 = vp_rot[bs*9+1], R02 = vp_rot[bs*9+2];
    const float R10 = vp_rot[bs*9+3], R11 = vp_rot[bs*9+4], R12 = vp_rot[bs*9+5];
    const float R20 = vp_rot[bs*9+6], R21 = vp_rot[bs*9+7], R22 = vp_rot[bs*9+8];

    const int lx = max(0, (int)floorf((sx - 0.066f) * 16.f));
    const int hx = min(7, (int)floorf((sx + 0.066f) * 16.f));
    const int ly = max(0, (int)floorf((sy - 0.066f) * 16.f));
    const int hy = min(7, (int)floorf((sy + 0.066f) * 16.f));
    const int lz = max(0, (int)floorf((sz - 0.066f) * 16.f));
    const int hz = min(7, (int)floorf((sz + 0.066f) * 16.f));
    const int nx = hx - lx + 1, ny = hy - ly + 1, nz = hz - lz + 1;
    const int ncell = nx * ny * nz;     // <= 64

    if (tid < ncell) {
        int cz = lz + tid / (nx * ny);
        int rem = tid % (nx * ny);
        int cy = ly + rem / nx;
        int cx = lx + rem % nx;
        int cid = (cz * 8 + cy) * 8 + cx;
        sm.cstart[tid] = (int)offsets[b * 512 + cid];
        sm.ccnt[tid]   = (int)counts [b * 512 + cid];
    }
    __syncthreads();

    {
        #pragma clang fp contract(off)
        for (int k = wv; k < ncell; k += 4) {
            const int base = sm.cstart[k];
            const int cnt  = sm.ccnt[k];
            for (int i = ln; i < cnt; i += 64) {
                float4 pt = binned[base + i];
                float rx = pt.x - sx, ry = pt.y - sy, rz = pt.z - sz;
                float x = (rx*R00 + ry*R10) + rz*R20;
                float y = (rx*R01 + ry*R11) + rz*R21;
                float z = (rx*R02 + ry*R12) + rz*R22;
                if (((y*y + z*z) < 0.0025f) && (x > -0.02f) && (x < 0.04f)) {
                    int n = __float_as_int(pt.w);
                    unsigned int bit = 1u << (n & 31);
                    int wi = n >> 5;
                    if (x < 0.01f) atomicOr(&sm.bm[0][wi], bit);
                    if (x < 0.02f) atomicOr(&sm.bm[1][wi], bit);
                    if (x < 0.03f) atomicOr(&sm.bm[2][wi], bit);
                    atomicOr(&sm.bm[3][wi], bit);
                }
            }
        }
    }
    __syncthreads();

    {
        const int d = wv;
        int carry = 0;
        for (int r = 0; r < 5 && carry < 64; ++r) {
            int c = r*64 + ln;
            unsigned long long w = 0ULL;
            if (c < NCHUNK)
                w = ((unsigned long long)sm.bm[d][2*c+1] << 32)
                  |  (unsigned long long)sm.bm[d][2*c];
            int wc = __popcll(w);
            int incl = wc;
            #pragma unroll
            for (int off = 1; off < 64; off <<= 1) {
                int t = __shfl_up(incl, off);
                if (ln >= off) incl += t;
            }
            int rank  = carry + incl - wc;
            int total = __shfl(incl, 63);
            while (w && rank < 64) {
                int bp = __builtin_ctzll(w);
                w &= w - 1;
                sm.idxs[d][rank] = c*64 + bp;
                ++rank;
            }
            carry += total;
        }
        int cnt = carry < 64 ? carry : 64;
        int first = (cnt > 0) ? sm.idxs[d][0] : 0;
        int v = (ln < cnt) ? sm.idxs[d][ln] : first;
        idx_out[(bs*4 + d)*64 + ln] = (unsigned short)v;
    }
}

// =============== K_mlp: R30 d-PAIRED MLP ===================================
// R29 gave the phase split: mlp = 104.8us of the 115. d-pairing processes
// d in pairs with a dd-loop INSIDE the rolled m-loops: each L2-hot weight
// row load is amortized over 2x MFMA work, and barriers halve (8 -> 4).
// Register cost ~+3 (acc/rm/bb reused sequentially across dd) — unlike
// R23/R25/R27 this does not duplicate live state. Enabled by the split:
// h1[2]+h2[2] (53.2KB) only fits 3 blocks/CU without the scan bitmap union.
// LDS 54272 x 3 = 162816 <= 163840. Per-d arithmetic bit-identical.
struct __align__(16) SMemM {
    unsigned short h1[2][64][72];   // 18432 B [pair-slot][sample][ch] +8 pad
    unsigned short h2[2][64][136];  // 34816 B
    float w1e[64][3];               // BN1-absorbed layer-1 weights
    float b1e[64];
};

__global__ __launch_bounds__(256, 3)
void mlp_kernel(const float* __restrict__ seed_xyz,
                const float* __restrict__ pointcloud,
                const float* __restrict__ vp_rot,
                const unsigned short* __restrict__ idx_in,
                const unsigned short* __restrict__ w2p,
                const unsigned short* __restrict__ w3p,
                const float* __restrict__ w1e_g, const float* __restrict__ b1e_g,
                const float* __restrict__ b2e_g, const float* __restrict__ b3e_g,
                float* __restrict__ out)
{
    __shared__ SMemM sm;
    const int tid = threadIdx.x;
    const int wv  = tid >> 6;
    const int ln  = tid & 63;
    const int q   = ln >> 4;
    const int l15 = ln & 15;

    const int blk = blockIdx.x;
    const int i8  = blk >> 3;
    const int s   = (blk & 7) * 128 + (i8 & 127);
    const int b   = i8 >> 7;
    const int bs  = b * 1024 + s;

    if (tid < 64) {
        sm.w1e[tid][0] = w1e_g[tid*3+0];
        sm.w1e[tid][1] = w1e_g[tid*3+1];
        sm.w1e[tid][2] = w1e_g[tid*3+2];
        sm.b1e[tid]    = b1e_g[tid];
    }

    const float sx = seed_xyz[bs*3+0];
    const float sy = seed_xyz[bs*3+1];
    const float sz = seed_xyz[bs*3+2];
    const float R00 = vp_rot[bs*9+0], R01 = vp_rot[bs*9+1], R02 = vp_rot[bs*9+2];
    const float R10 = vp_rot[bs*9+3], R11 = vp_rot[bs*9+4], R12 = vp_rot[bs*9+5];
    const float R20 = vp_rot[bs*9+6], R21 = vp_rot[bs*9+7], R22 = vp_rot[bs*9+8];

    // L1 compute into pair-slot dd. Bit-identical fma trees per channel.
    auto l1_compute = [&](int dd, float p0, float p1, float p2) {
        float x0, x1, x2;
        {
            #pragma clang fp contract(off)
            float rx = p0 - sx, ry = p1 - sy, rz = p2 - sz;
            x0 = (rx*R00 + ry*R10) + rz*R20;
            x1 = (rx*R01 + ry*R11) + rz*R21;
            x2 = (rx*R02 + ry*R12) + rz*R22;
        }
        unsigned int pk[8];
        #pragma unroll
        for (int i = 0; i < 8; ++i) {
            int ch = wv*16 + i*2;
            float ha = fmaf(x0, sm.w1e[ch][0],
                       fmaf(x1, sm.w1e[ch][1],
                       fmaf(x2, sm.w1e[ch][2], sm.b1e[ch])));
            float hb = fmaf(x0, sm.w1e[ch+1][0],
                       fmaf(x1, sm.w1e[ch+1][1],
                       fmaf(x2, sm.w1e[ch+1][2], sm.b1e[ch+1])));
            pk[i] = pk2(fmaxf(ha, 0.f), fmaxf(hb, 0.f));
        }
        *(uint4*)&sm.h1[dd][ln][wv*16 + 0] = make_uint4(pk[0], pk[1], pk[2], pk[3]);
        *(uint4*)&sm.h1[dd][ln][wv*16 + 8] = make_uint4(pk[4], pk[5], pk[6], pk[7]);
    };

    __syncthreads();    // w1e/b1e visible

    {   // L1 for d=0,1 (both loads issued before either compute)
        int n0 = (int)idx_in[(bs*4 + 0)*64 + ln];
        int n1 = (int)idx_in[(bs*4 + 1)*64 + ln];
        const float* p0 = pointcloud + (b*NPTS + n0)*3;
        const float* p1 = pointcloud + (b*NPTS + n1)*3;
        float a0 = p0[0], a1 = p0[1], a2 = p0[2];
        float c0 = p1[0], c1 = p1[1], c2 = p1[2];
        l1_compute(0, a0, a1, a2);
        l1_compute(1, c0, c1, c2);
    }
    __syncthreads();

    for (int dp = 0; dp < 2; ++dp) {
        // next pair's point loads issued EARLY (hide under L2+L3)
        float px0 = 0.f, py0 = 0.f, pz0 = 0.f;
        float px1 = 0.f, py1 = 0.f, pz1 = 0.f;
        if (dp == 0) {
            int n0 = (int)idx_in[(bs*4 + 2)*64 + ln];
            int n1 = (int)idx_in[(bs*4 + 3)*64 + ln];
            const float* p0 = pointcloud + (b*NPTS + n0)*3;
            const float* p1 = pointcloud + (b*NPTS + n1)*3;
            px0 = p0[0]; py0 = p0[1]; pz0 = p0[2];
            px1 = p1[0]; py1 = p1[1]; pz1 = p1[2];
        }

        // layer 2: m-outer (ROLLED: anti-LICM); weight row loaded ONCE per
        // m, consumed by BOTH pair-slots (dd unrolled inside).
        {
            #pragma unroll 1
            for (int m = 0; m < 2; ++m) {
                int row = (wv*2+m)*16 + l15;
                bf16x8 a0 = *(const bf16x8*)(w2p + row*64 +  0 + q*8);
                bf16x8 a1 = *(const bf16x8*)(w2p + row*64 + 32 + q*8);
                f32x4 binit2 = *(const f32x4*)&b2e_g[(wv*2+m)*16 + q*4];
                #pragma unroll
                for (int dd = 0; dd < 2; ++dd) {
                    #pragma unroll
                    for (int nt = 0; nt < 4; ++nt) {
                        int n = nt*16 + l15;
                        bf16x8 b0 = *(const bf16x8*)&sm.h1[dd][n][q*8];
                        bf16x8 b1 = *(const bf16x8*)&sm.h1[dd][n][32 + q*8];
                        f32x4 acc = binit2;
                        acc = __builtin_amdgcn_mfma_f32_16x16x32_bf16(a0, b0, acc, 0, 0, 0);
                        acc = __builtin_amdgcn_mfma_f32_16x16x32_bf16(a1, b1, acc, 0, 0, 0);
                        int ch0 = (wv*2+m)*16 + q*4;
                        uint2 pkk;
                        pkk.x = pk2(fmaxf(acc[0], 0.f), fmaxf(acc[1], 0.f));
                        pkk.y = pk2(fmaxf(acc[2], 0.f), fmaxf(acc[3], 0.f));
                        *(uint2*)&sm.h2[dd][n][ch0] = pkk;
                    }
                }
            }
        }
        __syncthreads();

        // layer 3: m-outer (ROLLED: anti-LICM); 4 weight rows loaded ONCE
        // per m, consumed by BOTH pair-slots. acc/rm reused across dd.
        {
            #pragma unroll 1
            for (int m = 0; m < 4; ++m) {
                int row = (wv*4+m)*16 + l15;
                bf16x8 a0 = *(const bf16x8*)(w3p + row*128 +  0 + q*8);
                bf16x8 a1 = *(const bf16x8*)(w3p + row*128 + 32 + q*8);
                bf16x8 a2 = *(const bf16x8*)(w3p + row*128 + 64 + q*8);
                bf16x8 a3 = *(const bf16x8*)(w3p + row*128 + 96 + q*8);
                f32x4 binit3 = *(const f32x4*)&b3e_g[(wv*4+m)*16 + q*4];
                #pragma unroll
                for (int dd = 0; dd < 2; ++dd) {
                    float rm[4];
                    #pragma unroll
                    for (int r = 0; r < 4; ++r) rm[r] = 0.f;
                    #pragma unroll
                    for (int nt = 0; nt < 4; ++nt) {
                        int n = nt*16 + l15;
                        bf16x8 bb0 = *(const bf16x8*)&sm.h2[dd][n][ 0 + q*8];
                        bf16x8 bb1 = *(const bf16x8*)&sm.h2[dd][n][32 + q*8];
                        bf16x8 bb2 = *(const bf16x8*)&sm.h2[dd][n][64 + q*8];
                        bf16x8 bb3 = *(const bf16x8*)&sm.h2[dd][n][96 + q*8];
                        f32x4 acc = binit3;
                        acc = __builtin_amdgcn_mfma_f32_16x16x32_bf16(a0, bb0, acc, 0, 0, 0);
                        acc = __builtin_amdgcn_mfma_f32_16x16x32_bf16(a1, bb1, acc, 0, 0, 0);
                        acc = __builtin_amdgcn_mfma_f32_16x16x32_bf16(a2, bb2, acc, 0, 0, 0);
                        acc = __builtin_amdgcn_mfma_f32_16x16x32_bf16(a3, bb3, acc, 0, 0, 0);
                        #pragma unroll
                        for (int r = 0; r < 4; ++r)
                            rm[r] = fmaxf(rm[r], acc[r]);
                    }
                    #pragma unroll
                    for (int r = 0; r < 4; ++r) {
                        float v = rm[r];
                        v = fmaxf(v, __shfl_xor(v, 1));
                        v = fmaxf(v, __shfl_xor(v, 2));
                        v = fmaxf(v, __shfl_xor(v, 4));
                        v = fmaxf(v, __shfl_xor(v, 8));
                        if (l15 == 0) {
                            int ch = (wv*4+m)*16 + q*4 + r;
                            out[((b*256 + ch)*1024 + s)*4 + dp*2 + dd] = v;
                        }
                    }
                }
            }

            if (dp == 0) {
                l1_compute(0, px0, py0, pz0);
                l1_compute(1, px1, py1, pz1);
            }
        }
        if (dp == 0) __syncthreads();
    }
}

extern "C" void kernel_launch(void* const* d_in, const int* in_sizes, int n_in,
                              void* d_out, int out_size, void* d_ws, size_t ws_size,
                              hipStream_t stream) {
    (void)in_sizes; (void)n_in; (void)out_size; (void)ws_size;
    const float* seed = (const float*)d_in[0];
    const float* pc   = (const float*)d_in[1];
    const float* rot  = (const float*)d_in[2];
    const float* w1   = (const float*)d_in[3];
    const float* g1   = (const float*)d_in[4];
    const float* be1  = (const float*)d_in[5];
    const float* mn1  = (const float*)d_in[6];
    const float* vr1  = (const float*)d_in[7];
    const float* w2   = (const float*)d_in[8];
    const float* g2   = (const float*)d_in[9];
    const float* be2  = (const float*)d_in[10];
    const float* mn2  = (const float*)d_in[11];
    const float* vr2  = (const float*)d_in[12];
    const float* w3   = (const float*)d_in[13];
    const float* g3   = (const float*)d_in[14];
    const float* be3  = (const float*)d_in[15];
    const float* mn3  = (const float*)d_in[16];
    const float* vr3  = (const float*)d_in[17];

    char* ws = (char*)d_ws;
    float4*         binned   = (float4*)(ws + WS_BINNED);
    unsigned int*   parthist = (unsigned int*)(ws + WS_PARTHIST);
    unsigned int*   counts   = (unsigned int*)(ws + WS_COUNTS);
    unsigned int*   offsets  = (unsigned int*)(ws + WS_OFFSETS);
    unsigned short* w2p      = (unsigned short*)(ws + WS_W2P);
    unsigned short* w3p      = (unsigned short*)(ws + WS_W3P);
    float*          w1e_g    = (float*)(ws + WS_W1E);
    float*          b1e_g    = (float*)(ws + WS_B1E);
    float*          b2e_g    = (float*)(ws + WS_B2E);
    float*          b3e_g    = (float*)(ws + WS_B3E);
    unsigned short* idx_ws   = (unsigned short*)(ws + WS_IDX);

    hist_prepack_kernel<<<dim3(40), dim3(512), 0, stream>>>(
        pc,
        w1, g1, be1, mn1, vr1,
        w2, g2, be2, mn2, vr2,
        w3, g3, be3, mn3, vr3,
        parthist,
        w2p, w3p, w1e_g, b1e_g, b2e_g, b3e_g);
    scatter_kernel<<<dim3(40), dim3(512), 0, stream>>>(
        pc, parthist, counts, offsets, binned);
    scan_select_kernel<<<dim3(2048), dim3(256), 0, stream>>>(
        seed, rot, counts, offsets, binned, idx_ws);
    mlp_kernel<<<dim3(2048), dim3(256), 0, stream>>>(
        seed, pc, rot, idx_ws,
        w2p, w3p, w1e_g, b1e_g, b2e_g, b3e_g,
        (float*)d_out);
}

// Round 15
// 195.991 us; speedup vs baseline: 1.1855x; 1.1855x over previous
//
#include <hip/hip_runtime.h>

#define NPTS   20000
#define NCHUNK 313   // ceil(NPTS/64)

typedef __bf16 bf16x8 __attribute__((ext_vector_type(8)));
typedef float  f32x4  __attribute__((ext_vector_type(4)));

__device__ __forceinline__ unsigned short f2b(float f) {
    __bf16 h = (__bf16)f;                       // RNE fptrunc (hw cvt on gfx950)
    union { __bf16 h; unsigned short s; } u; u.h = h; return u.s;
}
__device__ __forceinline__ unsigned int pk2(float a, float b) {
    return (unsigned int)f2b(a) | ((unsigned int)f2b(b) << 16);
}

// ---------------- workspace layout ----------------
#define WS_BINNED    0          // 40000 float4 = 640000 B
#define WS_PARTHIST  640000     // 40*512 u32  =  81920 B
#define WS_COUNTS    721920     // 1024 u32
#define WS_OFFSETS   726016     // 1024 u32
#define WS_FLAGS     730112     // (unused since R18; kept for layout stability)
#define WS_W2P       730368     // 128*64  bf16 = 16384 B (BN2-scaled, packed)
#define WS_W3P       746752     // 256*128 bf16 = 65536 B (BN3-scaled, packed)
#define WS_W1E       812288     // 64*3 f32
#define WS_B1E       813056     // 64 f32
#define WS_B2E       813312     // 128 f32
#define WS_B3E       813824     // 256 f32

// =============== prep = 2 kernels (scan folded into scatter) ===============
// K1: per-partition shared-mem histogram (plain store to parthist)
//     + one-time BN-absorbed weight pre-pack.
__global__ __launch_bounds__(512)
void hist_prepack_kernel(const float* __restrict__ pointcloud,
                const float* __restrict__ w1,
                const float* __restrict__ g1,  const float* __restrict__ be1,
                const float* __restrict__ mn1, const float* __restrict__ vr1,
                const float* __restrict__ w2,
                const float* __restrict__ g2,  const float* __restrict__ be2,
                const float* __restrict__ mn2, const float* __restrict__ vr2,
                const float* __restrict__ w3,
                const float* __restrict__ g3,  const float* __restrict__ be3,
                const float* __restrict__ mn3, const float* __restrict__ vr3,
                unsigned int* __restrict__ parthist,
                unsigned short* __restrict__ w2p,
                unsigned short* __restrict__ w3p,
                float* __restrict__ w1e_g, float* __restrict__ b1e_g,
                float* __restrict__ b2e_g, float* __restrict__ b3e_g)
{
    __shared__ unsigned int h[512];
    const int blk = blockIdx.x;          // 0..39
    const int b   = blk / 20;
    const int p   = blk % 20;
    const int tid = threadIdx.x;
    const int gid = blk * 512 + tid;     // 0..20479

    // ---- weight pre-pack (spread across all threads) ----
    for (int e = gid; e < 8192; e += 20480) {          // w2p[128][64]
        int row = e >> 6;
        float inv = g2[row] / sqrtf(vr2[row] + 1e-5f);
        w2p[e] = f2b(w2[e] * inv);
    }
    for (int e = gid; e < 32768; e += 20480) {         // w3p[256][128]
        int row = e >> 7;
        float inv = g3[row] / sqrtf(vr3[row] + 1e-5f);
        w3p[e] = f2b(w3[e] * inv);
    }
    if (gid < 64) {
        float inv = g1[gid] / sqrtf(vr1[gid] + 1e-5f);
        w1e_g[gid*3+0] = inv * w1[gid*3+0];
        w1e_g[gid*3+1] = inv * w1[gid*3+1];
        w1e_g[gid*3+2] = inv * w1[gid*3+2];
        b1e_g[gid]     = be1[gid] - mn1[gid] * inv;
    }
    if (gid < 128) {
        float inv = g2[gid] / sqrtf(vr2[gid] + 1e-5f);
        b2e_g[gid] = be2[gid] - mn2[gid] * inv;
    }
    if (gid < 256) {
        float inv = g3[gid] / sqrtf(vr3[gid] + 1e-5f);
        b3e_g[gid] = be3[gid] - mn3[gid] * inv;
    }

    // ---- histogram of own 1000-point slice ----
    h[tid] = 0;
    __syncthreads();

    const float* base = pointcloud + (b * NPTS + p * 1000) * 3;
    for (int i = tid; i < 1000; i += 512) {
        float x = base[i*3+0], y = base[i*3+1], z = base[i*3+2];
        int cx = min(7, (int)(x * 16.0f));
        int cy = min(7, (int)(y * 16.0f));
        int cz = min(7, (int)(z * 16.0f));
        atomicAdd(&h[(cz * 8 + cy) * 8 + cx], 1u);
    }
    __syncthreads();

    parthist[blk * 512 + tid] = h[tid];   // plain store; stream orders K1->K2
}

// K2: per-partition scatter with inline scan. Each block recomputes its
// batch's 512-bin exclusive scan from parthist (plain coalesced loads);
// p==0 blocks also publish counts/offsets for fused.
__global__ __launch_bounds__(512)
void scatter_kernel(const float* __restrict__ pointcloud,
                    const unsigned int* __restrict__ parthist,
                    unsigned int* __restrict__ counts,
                    unsigned int* __restrict__ offsets,
                    float4* __restrict__ binned)
{
    __shared__ unsigned int scanv[512];
    __shared__ unsigned int cur[512];
    const int blk = blockIdx.x;          // 0..39
    const int b   = blk / 20;
    const int p   = blk % 20;
    const int tid = threadIdx.x;

    unsigned int cnt = 0, partial = 0;
    #pragma unroll
    for (int pp = 0; pp < 20; ++pp) {
        unsigned int v = parthist[(b * 20 + pp) * 512 + tid];
        cnt += v;
        if (pp < p) partial += v;
    }
    scanv[tid] = cnt;
    __syncthreads();
    #pragma unroll
    for (int off = 1; off < 512; off <<= 1) {
        unsigned int v = 0;
        if (tid >= off) v = scanv[tid - off];
        __syncthreads();
        scanv[tid] += v;
        __syncthreads();
    }
    unsigned int excl = scanv[tid] - cnt;
    if (p == 0) {
        counts [b * 512 + tid] = cnt;
        offsets[b * 512 + tid] = b * NPTS + excl;
    }
    cur[tid] = b * NPTS + excl + partial;
    __syncthreads();

    const float* base = pointcloud + (b * NPTS + p * 1000) * 3;
    for (int i = tid; i < 1000; i += 512) {
        float x = base[i*3+0], y = base[i*3+1], z = base[i*3+2];
        int cx = min(7, (int)(x * 16.0f));
        int cy = min(7, (int)(y * 16.0f));
        int cz = min(7, (int)(z * 16.0f));
        int cid = (cz * 8 + cy) * 8 + cx;
        unsigned int slot = atomicAdd(&cur[cid], 1u);
        binned[slot] = make_float4(x, y, z, __int_as_float(p * 1000 + i));
    }
}

// =============== FUSED grid-scan + MLP =====================================
// R31 = final revert to the R28 champion (fused 115us, VGPR 64, ~41% occ,
// total 196.4us). Complete falsification map (R22-R30):
//   - occupancy cap relax (R22): no effect past 40%;
//   - register pipelining, 4 flavors (R23/R25/R27/R30): every ≳+12 live
//     regs crosses the 64-VGPR cliff (spill or bucket drop > overlap gain);
//   - 8-wave blocks (R26): barrier skew + conflict growth;
//   - LDS-traffic halving (R27): conflicts live in scan atomics, not reads;
//   - kernel split (R29): cost-neutral (mlp=105us, scan=11us measured);
//   - d-pairing (R30): dd-unroll duplicated acc/rm live ranges, +20 regs.
// Residual = barrier-phased dependent-chain structure at ~48% issue util.
// Practical plateau for this decomposition.
struct __align__(16) SMemF {
    union {
        struct {
            unsigned int bm[4][640];    // 10240 B: 313 u64-words as u32 pairs
            int cstart[64];             // ncell can reach 64 (R7 bug)
            int ccnt[64];
        } a;
        struct {
            unsigned short h1[64][72];  //  9216 B [sample][ch] +8 pad
            unsigned short h2[64][136]; // 17408 B [sample][ch] +8 pad
        } b;
    } u;
    int    idxs[4][64];
    float  w1e[64][3];                  // BN1-absorbed layer-1 weights
    float  b1e[64];
};

__global__ __launch_bounds__(256, 3)
void fused_kernel(const float* __restrict__ seed_xyz,
                  const float* __restrict__ pointcloud,
                  const float* __restrict__ vp_rot,
                  const unsigned int* __restrict__ counts,
                  const unsigned int* __restrict__ offsets,
                  const float4* __restrict__ binned,
                  const unsigned short* __restrict__ w2p,
                  const unsigned short* __restrict__ w3p,
                  const float* __restrict__ w1e_g, const float* __restrict__ b1e_g,
                  const float* __restrict__ b2e_g, const float* __restrict__ b3e_g,
                  float* __restrict__ out)
{
    __shared__ SMemF sm;
    const int tid = threadIdx.x;
    const int wv  = tid >> 6;
    const int ln  = tid & 63;
    const int q   = ln >> 4;
    const int l15 = ln & 15;

    // XCD-aware swizzle: blocks writing the same output cache line (s..s+3)
    // share blk&7 -> same XCD under round-robin dispatch.
    const int blk = blockIdx.x;
    const int i8  = blk >> 3;
    const int s   = (blk & 7) * 128 + (i8 & 127);
    const int b   = i8 >> 7;
    const int bs  = b * 1024 + s;

    // ---- L1 constants from ws ----
    if (tid < 64) {
        sm.w1e[tid][0] = w1e_g[tid*3+0];
        sm.w1e[tid][1] = w1e_g[tid*3+1];
        sm.w1e[tid][2] = w1e_g[tid*3+2];
        sm.b1e[tid]    = b1e_g[tid];
    }

    // ---- zero bitmaps (2560 u32 = bm[4][640]) ----
    {
        unsigned int* bmp = &sm.u.a.bm[0][0];
        #pragma unroll
        for (int i = 0; i < 10; ++i) bmp[tid + i * 256] = 0;
    }

    const float sx = seed_xyz[bs*3+0];
    const float sy = seed_xyz[bs*3+1];
    const float sz = seed_xyz[bs*3+2];
    const float R00 = vp_rot[bs*9+0], R01 = vp_rot[bs*9+1], R02 = vp_rot[bs*9+2];
    const float R10 = vp_rot[bs*9+3], R11 = vp_rot[bs*9+4], R12 = vp_rot[bs*9+5];
    const float R20 = vp_rot[bs*9+6], R21 = vp_rot[bs*9+7], R22 = vp_rot[bs*9+8];

    // candidate cell range: cells overlapping [s-0.066, s+0.066]^3
    // (each dim spans 3 OR 4 cells -> ncell up to 64; R7 post-mortem)
    const int lx = max(0, (int)floorf((sx - 0.066f) * 16.f));
    const int hx = min(7, (int)floorf((sx + 0.066f) * 16.f));
    const int ly = max(0, (int)floorf((sy - 0.066f) * 16.f));
    const int hy = min(7, (int)floorf((sy + 0.066f) * 16.f));
    const int lz = max(0, (int)floorf((sz - 0.066f) * 16.f));
    const int hz = min(7, (int)floorf((sz + 0.066f) * 16.f));
    const int nx = hx - lx + 1, ny = hy - ly + 1, nz = hz - lz + 1;
    const int ncell = nx * ny * nz;     // <= 64

    if (tid < ncell) {
        int cz = lz + tid / (nx * ny);
        int rem = tid % (nx * ny);
        int cy = ly + rem / nx;
        int cx = lx + rem % nx;
        int cid = (cz * 8 + cy) * 8 + cx;
        sm.u.a.cstart[tid] = (int)offsets[b * 512 + cid];
        sm.u.a.ccnt[tid]   = (int)counts [b * 512 + cid];
    }
    __syncthreads();

    // ---- scan: cell-outer (wave wv takes cells wv, wv+4, ...), point-inner.
    // Mask uses exact fp32 contract(off) arithmetic; bits set order-
    // independently -> stage B semantics identical to brute-force.
    {
        #pragma clang fp contract(off)
        for (int k = wv; k < ncell; k += 4) {
            const int base = sm.u.a.cstart[k];
            const int cnt  = sm.u.a.ccnt[k];
            for (int i = ln; i < cnt; i += 64) {
                float4 pt = binned[base + i];
                float rx = pt.x - sx, ry = pt.y - sy, rz = pt.z - sz;
                float x = (rx*R00 + ry*R10) + rz*R20;
                float y = (rx*R01 + ry*R11) + rz*R21;
                float z = (rx*R02 + ry*R12) + rz*R22;
                if (((y*y + z*z) < 0.0025f) && (x > -0.02f) && (x < 0.04f)) {
                    int n = __float_as_int(pt.w);
                    unsigned int bit = 1u << (n & 31);
                    int wi = n >> 5;
                    if (x < 0.01f) atomicOr(&sm.u.a.bm[0][wi], bit);
                    if (x < 0.02f) atomicOr(&sm.u.a.bm[1][wi], bit);
                    if (x < 0.03f) atomicOr(&sm.u.a.bm[2][wi], bit);
                    atomicOr(&sm.u.a.bm[3][wi], bit);
                }
            }
        }
    }
    __syncthreads();

    // ---- stage B: ordered first-64 extraction (wave wv -> d=wv) ----
    {
        const int d = wv;
        int carry = 0;
        for (int r = 0; r < 5 && carry < 64; ++r) {
            int c = r*64 + ln;
            unsigned long long w = 0ULL;
            if (c < NCHUNK)
                w = ((unsigned long long)sm.u.a.bm[d][2*c+1] << 32)
                  |  (unsigned long long)sm.u.a.bm[d][2*c];
            int wc = __popcll(w);
            int incl = wc;
            #pragma unroll
            for (int off = 1; off < 64; off <<= 1) {
                int t = __shfl_up(incl, off);
                if (ln >= off) incl += t;
            }
            int rank  = carry + incl - wc;
            int total = __shfl(incl, 63);
            while (w && rank < 64) {
                int bp = __builtin_ctzll(w);
                w &= w - 1;
                sm.idxs[d][rank] = c*64 + bp;
                ++rank;
            }
            carry += total;
        }
        int cnt = carry < 64 ? carry : 64;
        int first = (cnt > 0) ? sm.idxs[d][0] : 0;
        if (ln >= cnt) sm.idxs[d][ln] = first;
    }

    __syncthreads();    // idxs visible; bm/cstart/ccnt dead -> h1/h2 may reuse

    // L1 compute (loads split out): lane ln holds point coords of
    // idxs[d][ln]; exact contract(off) rel_rot, 16 channels of BN1-absorbed
    // fma -> h1[ln][wv*16..]. Bit-identical to the fused original.
    auto l1_compute = [&](float p0, float p1, float p2) {
        float x0, x1, x2;
        {
            #pragma clang fp contract(off)
            float rx = p0 - sx, ry = p1 - sy, rz = p2 - sz;
            x0 = (rx*R00 + ry*R10) + rz*R20;
            x1 = (rx*R01 + ry*R11) + rz*R21;
            x2 = (rx*R02 + ry*R12) + rz*R22;
        }
        unsigned int pk[8];
        #pragma unroll
        for (int i = 0; i < 8; ++i) {
            int ch = wv*16 + i*2;
            float ha = fmaf(x0, sm.w1e[ch][0],
                       fmaf(x1, sm.w1e[ch][1],
                       fmaf(x2, sm.w1e[ch][2], sm.b1e[ch])));
            float hb = fmaf(x0, sm.w1e[ch+1][0],
                       fmaf(x1, sm.w1e[ch+1][1],
                       fmaf(x2, sm.w1e[ch+1][2], sm.b1e[ch+1])));
            pk[i] = pk2(fmaxf(ha, 0.f), fmaxf(hb, 0.f));
        }
        *(uint4*)&sm.u.b.h1[ln][wv*16 + 0] = make_uint4(pk[0], pk[1], pk[2], pk[3]);
        *(uint4*)&sm.u.b.h1[ln][wv*16 + 8] = make_uint4(pk[4], pk[5], pk[6], pk[7]);
    };

    {   // L1(0): load + compute
        int n = sm.idxs[0][ln];
        const float* p = pointcloud + (b*NPTS + n)*3;
        l1_compute(p[0], p[1], p[2]);
    }
    __syncthreads();

    for (int d = 0; d < 4; ++d) {
        // ---- L1(d+1) point loads issued EARLY: latency hides under the
        // whole L2+L3 phase. h1 write happens later (after post-L2 barrier).
        float px = 0.f, py = 0.f, pz = 0.f;
        if (d < 3) {
            int n = sm.idxs[d+1][ln];
            const float* p = pointcloud + (b*NPTS + n)*3;
            px = p[0]; py = p[1]; pz = p[2];
        }

        // layer 2: M=128, K=64, N=64; m-outer (ROLLED: anti-LICM), aw2 row
        // streamed from w2p (L2-hot broadcast); acc init = BN2 bias.
        {
            #pragma unroll 1
            for (int m = 0; m < 2; ++m) {
                int row = (wv*2+m)*16 + l15;
                bf16x8 a0 = *(const bf16x8*)(w2p + row*64 +  0 + q*8);
                bf16x8 a1 = *(const bf16x8*)(w2p + row*64 + 32 + q*8);
                f32x4 binit2 = *(const f32x4*)&b2e_g[(wv*2+m)*16 + q*4];
                #pragma unroll
                for (int nt = 0; nt < 4; ++nt) {
                    int n = nt*16 + l15;
                    bf16x8 b0 = *(const bf16x8*)&sm.u.b.h1[n][q*8];
                    bf16x8 b1 = *(const bf16x8*)&sm.u.b.h1[n][32 + q*8];
                    f32x4 acc = binit2;
                    acc = __builtin_amdgcn_mfma_f32_16x16x32_bf16(a0, b0, acc, 0, 0, 0);
                    acc = __builtin_amdgcn_mfma_f32_16x16x32_bf16(a1, b1, acc, 0, 0, 0);
                    int ch0 = (wv*2+m)*16 + q*4;
                    uint2 pkk;
                    pkk.x = pk2(fmaxf(acc[0], 0.f), fmaxf(acc[1], 0.f));
                    pkk.y = pk2(fmaxf(acc[2], 0.f), fmaxf(acc[3], 0.f));
                    *(uint2*)&sm.u.b.h2[n][ch0] = pkk;
                }
            }
        }
        __syncthreads();

        // layer 3: M=256, K=128; m-outer (ROLLED: anti-LICM), aw3 row
        // streamed from w3p per m; rm per-m with reduce+store inside the
        // m-loop. acc init = BN3 bias; ReLU folds into rm>=0.
        {
            #pragma unroll 1
            for (int m = 0; m < 4; ++m) {
                int row = (wv*4+m)*16 + l15;
                bf16x8 a0 = *(const bf16x8*)(w3p + row*128 +  0 + q*8);
                bf16x8 a1 = *(const bf16x8*)(w3p + row*128 + 32 + q*8);
                bf16x8 a2 = *(const bf16x8*)(w3p + row*128 + 64 + q*8);
                bf16x8 a3 = *(const bf16x8*)(w3p + row*128 + 96 + q*8);
                f32x4 binit3 = *(const f32x4*)&b3e_g[(wv*4+m)*16 + q*4];
                float rm[4];
                #pragma unroll
                for (int r = 0; r < 4; ++r) rm[r] = 0.f;
                #pragma unroll
                for (int nt = 0; nt < 4; ++nt) {
                    int n = nt*16 + l15;
                    bf16x8 bb0 = *(const bf16x8*)&sm.u.b.h2[n][ 0 + q*8];
                    bf16x8 bb1 = *(const bf16x8*)&sm.u.b.h2[n][32 + q*8];
                    bf16x8 bb2 = *(const bf16x8*)&sm.u.b.h2[n][64 + q*8];
                    bf16x8 bb3 = *(const bf16x8*)&sm.u.b.h2[n][96 + q*8];
                    f32x4 acc = binit3;
                    acc = __builtin_amdgcn_mfma_f32_16x16x32_bf16(a0, bb0, acc, 0, 0, 0);
                    acc = __builtin_amdgcn_mfma_f32_16x16x32_bf16(a1, bb1, acc, 0, 0, 0);
                    acc = __builtin_amdgcn_mfma_f32_16x16x32_bf16(a2, bb2, acc, 0, 0, 0);
                    acc = __builtin_amdgcn_mfma_f32_16x16x32_bf16(a3, bb3, acc, 0, 0, 0);
                    #pragma unroll
                    for (int r = 0; r < 4; ++r)
                        rm[r] = fmaxf(rm[r], acc[r]);
                }
                #pragma unroll
                for (int r = 0; r < 4; ++r) {
                    float v = rm[r];
                    v = fmaxf(v, __shfl_xor(v, 1));
                    v = fmaxf(v, __shfl_xor(v, 2));
                    v = fmaxf(v, __shfl_xor(v, 4));
                    v = fmaxf(v, __shfl_xor(v, 8));
                    if (l15 == 0) {
                        int ch = (wv*4+m)*16 + q*4 + r;
                        out[((b*256 + ch)*1024 + s)*4 + d] = v;
                    }
                }
            }

            if (d < 3) l1_compute(px, py, pz);
        }
        if (d < 3) __syncthreads();
    }
}

extern "C" void kernel_launch(void* const* d_in, const int* in_sizes, int n_in,
                              void* d_out, int out_size, void* d_ws, size_t ws_size,
                              hipStream_t stream) {
    (void)in_sizes; (void)n_in; (void)out_size; (void)ws_size;
    const float* seed = (const float*)d_in[0];
    const float* pc   = (const float*)d_in[1];
    const float* rot  = (const float*)d_in[2];
    const float* w1   = (const float*)d_in[3];
    const float* g1   = (const float*)d_in[4];
    const float* be1  = (const float*)d_in[5];
    const float* mn1  = (const float*)d_in[6];
    const float* vr1  = (const float*)d_in[7];
    const float* w2   = (const float*)d_in[8];
    const float* g2   = (const float*)d_in[9];
    const float* be2  = (const float*)d_in[10];
    const float* mn2  = (const float*)d_in[11];
    const float* vr2  = (const float*)d_in[12];
    const float* w3   = (const float*)d_in[13];
    const float* g3   = (const float*)d_in[14];
    const float* be3  = (const float*)d_in[15];
    const float* mn3  = (const float*)d_in[16];
    const float* vr3  = (const float*)d_in[17];

    char* ws = (char*)d_ws;
    float4*         binned   = (float4*)(ws + WS_BINNED);
    unsigned int*   parthist = (unsigned int*)(ws + WS_PARTHIST);
    unsigned int*   counts   = (unsigned int*)(ws + WS_COUNTS);
    unsigned int*   offsets  = (unsigned int*)(ws + WS_OFFSETS);
    unsigned short* w2p      = (unsigned short*)(ws + WS_W2P);
    unsigned short* w3p      = (unsigned short*)(ws + WS_W3P);
    float*          w1e_g    = (float*)(ws + WS_W1E);
    float*          b1e_g    = (float*)(ws + WS_B1E);
    float*          b2e_g    = (float*)(ws + WS_B2E);
    float*          b3e_g    = (float*)(ws + WS_B3E);

    hist_prepack_kernel<<<dim3(40), dim3(512), 0, stream>>>(
        pc,
        w1, g1, be1, mn1, vr1,
        w2, g2, be2, mn2, vr2,
        w3, g3, be3, mn3, vr3,
        parthist,
        w2p, w3p, w1e_g, b1e_g, b2e_g, b3e_g);
    scatter_kernel<<<dim3(40), dim3(512), 0, stream>>>(
        pc, parthist, counts, offsets, binned);
    fused_kernel  <<<dim3(2048), dim3(256), 0, stream>>>(
        seed, pc, rot, counts, offsets, binned,
        w2p, w3p, w1e_g, b1e_g, b2e_g, b3e_g,
        (float*)d_out);
}